// Round 14
// baseline (264.235 us; speedup 1.0000x reference)
//
#include <hip/hip_runtime.h>
#include <stdint.h>

typedef _Float16 half8  __attribute__((ext_vector_type(8)));
typedef _Float16 half4v __attribute__((ext_vector_type(4)));
typedef __fp16   fp16x2 __attribute__((ext_vector_type(2)));
typedef float    floatx4 __attribute__((ext_vector_type(4)));
typedef float    floatx16 __attribute__((ext_vector_type(16)));

#define LOG2E 1.44269504088896340736f

// async global->LDS 16B copy (LDS dest must be wave-uniform base + lane*16)
__device__ __forceinline__ void gl_lds16(const _Float16* g, _Float16* l) {
  __builtin_amdgcn_global_load_lds(
      (__attribute__((address_space(1))) void*)g,
      (__attribute__((address_space(3))) void*)l, 16, 0, 0);
}

__device__ __forceinline__ half4v pack4(float a, float b, float c, float d) {
  auto lo = __builtin_amdgcn_cvt_pkrtz(a, b);
  auto hi = __builtin_amdgcn_cvt_pkrtz(c, d);
  return half4v{static_cast<_Float16>(lo[0]), static_cast<_Float16>(lo[1]),
                static_cast<_Float16>(hi[0]), static_cast<_Float16>(hi[1])};
}

// ---------------- kernel 1: fp32 -> f16 convert (X streams + weights) --------
struct CvtArgs {
  const float* sx[3];
  const float* sw[3];
  _Float16*    dx;     // [3][6291456]
  _Float16*    dw;     // [3][589824]
};

__global__ void cvt_kernel(CvtArgs a) {
  const int z  = blockIdx.y;
  const int bx = blockIdx.x;
  const float* src;
  _Float16*    dst;
  int base;
  if (bx < 3072) { src = a.sx[z]; dst = a.dx + (size_t)z * 6291456; base = bx * 2048; }
  else           { src = a.sw[z]; dst = a.dw + (size_t)z * 589824;  base = (bx - 3072) * 2048; }
  const int i = base + threadIdx.x * 8;
  const float4* s = (const float4*)(src + i);
  float4 v0 = s[0], v1 = s[1];
  half8 h = { (_Float16)v0.x, (_Float16)v0.y, (_Float16)v0.z, (_Float16)v0.w,
              (_Float16)v1.x, (_Float16)v1.y, (_Float16)v1.z, (_Float16)v1.w };
  *(half8*)(dst + i) = h;
}

// ---------------- kernel 2: QKV projection GEMM (r7/r8 structure, proven) ----
// f16 inputs, gl_lds staging, 3 LDS buffers, counted s_waitcnt vmcnt(4).
// 98 -> ~50 us measured (r7); r8 XCD swizzle null but harmless - kept.

__device__ __forceinline__ void gemm_stage16(const _Float16* __restrict__ P,
                                             _Float16* sb, int r0, int k0, int tid) {
  #pragma unroll
  for (int i = 0; i < 2; ++i) {          // 128 rows x 32 halfs = 8KB
    int G = i * 256 + tid;
    int r = G >> 2, gl = G & 3;
    int g = gl ^ ((r >> 1) & 3);
    gl_lds16(P + (size_t)(r0 + r) * 768 + k0 + g * 8, sb + G * 8);
  }
}

template <int RB, int WB, int VM, bool PREF>
__device__ __forceinline__ void gemm_body(
    int kpre, const _Float16* __restrict__ X, const _Float16* __restrict__ W,
    _Float16* As, _Float16* Bs, int m0, int n0, int tid, int z,
    int wr, int wc, int qd, int col, floatx4 (&acc)[4][4])
{
  asm volatile("s_waitcnt vmcnt(%0)" :: "i"(VM) : "memory");
  __builtin_amdgcn_s_barrier();
  __builtin_amdgcn_sched_barrier(0);
  if (PREF) {
    gemm_stage16(X, As + WB * 4096, m0, kpre, tid);
    gemm_stage16(W, Bs + WB * 4096, n0, kpre, tid);
  }
  __builtin_amdgcn_sched_barrier(0);

  half8 af[4], bf[4];
  #pragma unroll
  for (int t = 0; t < 4; ++t) {
    int ra = wr * 64 + t * 16 + col;
    af[t] = *(const half8*)(As + RB * 4096 + ra * 32 + ((qd ^ ((ra >> 1) & 3)) * 8));
  }
  #pragma unroll
  for (int t = 0; t < 4; ++t) {
    int rb = wc * 64 + t * 16 + col;
    bf[t] = *(const half8*)(Bs + RB * 4096 + rb * 32 + ((qd ^ ((rb >> 1) & 3)) * 8));
  }
  if (z == 2) {
    #pragma unroll
    for (int i = 0; i < 4; ++i)
      #pragma unroll
      for (int j = 0; j < 4; ++j)
        acc[i][j] = __builtin_amdgcn_mfma_f32_16x16x32_f16(af[i], bf[j], acc[i][j], 0, 0, 0);
  } else {
    #pragma unroll
    for (int i = 0; i < 4; ++i)
      #pragma unroll
      for (int j = 0; j < 4; ++j)
        acc[i][j] = __builtin_amdgcn_mfma_f32_16x16x32_f16(bf[j], af[i], acc[i][j], 0, 0, 0);
  }
}

__global__ __launch_bounds__(256, 2) void qkv_gemm(
    const _Float16* __restrict__ xh,   // [3][8192][768] f16
    const _Float16* __restrict__ wh,   // [3][768][768]  f16
    const float* __restrict__ bqp, const float* __restrict__ bkp, const float* __restrict__ bvp,
    _Float16* __restrict__ oq, _Float16* __restrict__ ok, _Float16* __restrict__ ovt)
{
  __shared__ __attribute__((aligned(16))) char smem[49152];
  _Float16* As = (_Float16*)smem;                 // 3 bufs x 4096 f16 = 24 KB
  _Float16* Bs = (_Float16*)(smem + 24576);       // 3 bufs x 4096 f16 = 24 KB
  _Float16* Es = (_Float16*)smem;                 // epilogue 128 x 160 halfs = 40 KB

  const int flat = blockIdx.x;         // 0..1151
  const int z    = flat / 384;
  const int f    = flat % 384;
  const int xcd  = f & 7;
  const int slot = f >> 3;             // 0..47
  const int n0 = (slot % 6) * 128;
  const int m0 = (xcd + 8 * (slot / 6)) * 128;

  const _Float16* X = xh + (size_t)z * 6291456;
  const _Float16* W = wh + (size_t)z * 589824;
  const int tid  = threadIdx.x;
  const int lane = tid & 63, wid = tid >> 6;
  const int wr = wid >> 1, wc = wid & 1;
  const int qd = lane >> 4, col = lane & 15;

  const floatx4 z4 = {0.f, 0.f, 0.f, 0.f};
  floatx4 acc[4][4];
  #pragma unroll
  for (int i = 0; i < 4; ++i)
    #pragma unroll
    for (int j = 0; j < 4; ++j) acc[i][j] = z4;

  gemm_stage16(X, As,        m0, 0,  tid);
  gemm_stage16(W, Bs,        n0, 0,  tid);
  gemm_stage16(X, As + 4096, m0, 32, tid);
  gemm_stage16(W, Bs + 4096, n0, 32, tid);

  int jn = 64;
  #pragma unroll 1
  for (int it = 0; it < 7; ++it) {
    gemm_body<0, 2, 4, true>(jn,      X, W, As, Bs, m0, n0, tid, z, wr, wc, qd, col, acc);
    gemm_body<1, 0, 4, true>(jn + 32, X, W, As, Bs, m0, n0, tid, z, wr, wc, qd, col, acc);
    gemm_body<2, 1, 4, true>(jn + 64, X, W, As, Bs, m0, n0, tid, z, wr, wc, qd, col, acc);
    jn += 96;
  }
  gemm_body<0, 2, 4, true >(736, X, W, As, Bs, m0, n0, tid, z, wr, wc, qd, col, acc);
  gemm_body<1, 0, 4, false>(0,   X, W, As, Bs, m0, n0, tid, z, wr, wc, qd, col, acc);
  gemm_body<2, 1, 0, false>(0,   X, W, As, Bs, m0, n0, tid, z, wr, wc, qd, col, acc);

  __syncthreads();

  const float* bias = (z == 0) ? bqp : ((z == 1) ? bkp : bvp);
  const int b = m0 >> 11, s0 = m0 & 2047;
  if (z == 2) {
    #pragma unroll
    for (int j = 0; j < 4; ++j) {
      int n_loc = wc * 64 + j * 16 + col;
      float bb = bias[n0 + n_loc];
      #pragma unroll
      for (int i = 0; i < 4; ++i) {
        int s_loc = wr * 64 + i * 16 + qd * 4;
        half4v h = pack4(acc[i][j][0] + bb, acc[i][j][1] + bb,
                         acc[i][j][2] + bb, acc[i][j][3] + bb);
        *(half4v*)(Es + n_loc * 160 + s_loc) = h;
      }
    }
    __syncthreads();
    #pragma unroll
    for (int it = 0; it < 8; ++it) {
      int row = it * 16 + (tid >> 4);
      int k   = tid & 15;
      half8 vr = *(const half8*)(Es + row * 160 + k * 8);
      *(half8*)(ovt + ((size_t)(b * 768 + n0 + row)) * 2048 + s0 + k * 8) = vr;
    }
  } else {
    _Float16* O = (z == 0) ? oq : ok;
    const float scale = (z == 0) ? LOG2E : 1.0f;
    #pragma unroll
    for (int j = 0; j < 4; ++j) {
      int n_loc = wc * 64 + j * 16 + qd * 4;
      float4 bb = *(const float4*)(bias + n0 + n_loc);
      #pragma unroll
      for (int i = 0; i < 4; ++i) {
        int s_loc = wr * 64 + i * 16 + col;
        half4v h = pack4((acc[i][j][0] + bb.x) * scale, (acc[i][j][1] + bb.y) * scale,
                         (acc[i][j][2] + bb.z) * scale, (acc[i][j][3] + bb.w) * scale);
        *(half4v*)(Es + s_loc * 160 + n_loc) = h;
      }
    }
    __syncthreads();
    const int hh0 = n0 >> 6;
    #pragma unroll
    for (int it = 0; it < 8; ++it) {
      int seg = it * 32 + (tid >> 3);
      int s = seg >> 1, hseg = seg & 1;
      int k = tid & 7;
      half8 vr = *(const half8*)(Es + s * 160 + hseg * 64 + k * 8);
      int mb = (m0 + s) >> 11, sg = (m0 + s) & 2047;
      *(half8*)(O + (size_t)(mb * 12 + hh0 + hseg) * 131072
                  + (size_t)sg * 64 + k * 8) = vr;
    }
  }
}

// ---------------- fallback QKV (r6 persistent, fp32 inputs) ------------------

__device__ __forceinline__ void issue_panel(const float* __restrict__ P,
                                            int r0, int k0, int tid,
                                            float4& a0, float4& a1,
                                            float4& b0, float4& b1) {
  {
    int G = tid;
    int r = G >> 2, gl = G & 3;
    int g = gl ^ ((r >> 1) & 3);
    const float4* s = (const float4*)(P + (size_t)(r0 + r) * 768 + k0 + g * 8);
    a0 = s[0]; a1 = s[1];
  }
  {
    int G = 256 + tid;
    int r = G >> 2, gl = G & 3;
    int g = gl ^ ((r >> 1) & 3);
    const float4* s = (const float4*)(P + (size_t)(r0 + r) * 768 + k0 + g * 8);
    b0 = s[0]; b1 = s[1];
  }
}

__device__ __forceinline__ void write_panel(_Float16* sb, int tid,
                                            const float4& a0, const float4& a1,
                                            const float4& b0, const float4& b1) {
  half8 h0 = { (_Float16)a0.x, (_Float16)a0.y, (_Float16)a0.z, (_Float16)a0.w,
               (_Float16)a1.x, (_Float16)a1.y, (_Float16)a1.z, (_Float16)a1.w };
  *(half8*)(sb + tid * 8) = h0;
  half8 h1 = { (_Float16)b0.x, (_Float16)b0.y, (_Float16)b0.z, (_Float16)b0.w,
               (_Float16)b1.x, (_Float16)b1.y, (_Float16)b1.z, (_Float16)b1.w };
  *(half8*)(sb + (256 + tid) * 8) = h1;
}

template <int BUF>
__device__ __forceinline__ void gemm_body_f32(
    int knext, const float* __restrict__ X, const float* __restrict__ W,
    _Float16* As, _Float16* Bs, int m0, int n0, int tid, int z,
    int wr, int wc, int qd, int col, floatx4 (&acc)[4][4])
{
  const bool pref = (knext < 768);
  float4 xa0, xa1, xb0, xb1, wa0, wa1, wb0, wb1;
  if (pref) {
    issue_panel(X, m0, knext, tid, xa0, xa1, xb0, xb1);
    issue_panel(W, n0, knext, tid, wa0, wa1, wb0, wb1);
  }

  half8 af[4], bf[4];
  #pragma unroll
  for (int t = 0; t < 4; ++t) {
    int ra = wr * 64 + t * 16 + col;
    af[t] = *(const half8*)(As + BUF * 4096 + ra * 32 + ((qd ^ ((ra >> 1) & 3)) * 8));
  }
  #pragma unroll
  for (int t = 0; t < 4; ++t) {
    int rb = wc * 64 + t * 16 + col;
    bf[t] = *(const half8*)(Bs + BUF * 4096 + rb * 32 + ((qd ^ ((rb >> 1) & 3)) * 8));
  }
  if (z == 2) {
    #pragma unroll
    for (int i = 0; i < 4; ++i)
      #pragma unroll
      for (int j = 0; j < 4; ++j)
        acc[i][j] = __builtin_amdgcn_mfma_f32_16x16x32_f16(af[i], bf[j], acc[i][j], 0, 0, 0);
  } else {
    #pragma unroll
    for (int i = 0; i < 4; ++i)
      #pragma unroll
      for (int j = 0; j < 4; ++j)
        acc[i][j] = __builtin_amdgcn_mfma_f32_16x16x32_f16(bf[j], af[i], acc[i][j], 0, 0, 0);
  }

  if (pref) {
    write_panel(As + (1 - BUF) * 4096, tid, xa0, xa1, xb0, xb1);
    write_panel(Bs + (1 - BUF) * 4096, tid, wa0, wa1, wb0, wb1);
  }
  __syncthreads();
}

__global__ __launch_bounds__(256, 2) void qkv_gemm_f32(
    const float* __restrict__ qx, const float* __restrict__ kx, const float* __restrict__ vx,
    const float* __restrict__ Wqp, const float* __restrict__ Wkp, const float* __restrict__ Wvp,
    const float* __restrict__ bqp, const float* __restrict__ bkp, const float* __restrict__ bvp,
    _Float16* __restrict__ oq, _Float16* __restrict__ ok, _Float16* __restrict__ ovt)
{
  __shared__ __attribute__((aligned(16))) char smem[40960];
  _Float16* As = (_Float16*)smem;
  _Float16* Bs = (_Float16*)(smem + 16384);
  _Float16* Es = (_Float16*)smem;

  const int tid  = threadIdx.x;
  const int lane = tid & 63, wid = tid >> 6;
  const int wr = wid >> 1, wc = wid & 1;
  const int qd = lane >> 4, col = lane & 15;

  #pragma unroll 1
  for (int t = blockIdx.x; t < 1152; t += 512) {
    const int m0 = (t & 63) * 128;
    const int n0 = ((t >> 6) % 6) * 128;
    const int z  = t / 384;
    const float* X = (z == 0) ? qx : ((z == 1) ? kx : vx);
    const float* W = (z == 0) ? Wqp : ((z == 1) ? Wkp : Wvp);

    const floatx4 z4 = {0.f, 0.f, 0.f, 0.f};
    floatx4 acc[4][4];
    #pragma unroll
    for (int i = 0; i < 4; ++i)
      #pragma unroll
      for (int j = 0; j < 4; ++j) acc[i][j] = z4;

    {
      float4 xa0, xa1, xb0, xb1, wa0, wa1, wb0, wb1;
      issue_panel(X, m0, 0, tid, xa0, xa1, xb0, xb1);
      issue_panel(W, n0, 0, tid, wa0, wa1, wb0, wb1);
      __syncthreads();
      write_panel(As, tid, xa0, xa1, xb0, xb1);
      write_panel(Bs, tid, wa0, wa1, wb0, wb1);
    }
    __syncthreads();
    for (int kk = 0; kk < 768; kk += 64) {
      gemm_body_f32<0>(kk + 32, X, W, As, Bs, m0, n0, tid, z, wr, wc, qd, col, acc);
      gemm_body_f32<1>(kk + 64, X, W, As, Bs, m0, n0, tid, z, wr, wc, qd, col, acc);
    }

    const float* bias = (z == 0) ? bqp : ((z == 1) ? bkp : bvp);
    const int b = m0 >> 11, s0 = m0 & 2047;
    if (z == 2) {
      #pragma unroll
      for (int j = 0; j < 4; ++j) {
        int n_loc = wc * 64 + j * 16 + col;
        float bb = bias[n0 + n_loc];
        #pragma unroll
        for (int i = 0; i < 4; ++i) {
          int s_loc = wr * 64 + i * 16 + qd * 4;
          half4v h = pack4(acc[i][j][0] + bb, acc[i][j][1] + bb,
                           acc[i][j][2] + bb, acc[i][j][3] + bb);
          *(half4v*)(Es + n_loc * 160 + s_loc) = h;
        }
      }
      __syncthreads();
      #pragma unroll
      for (int it = 0; it < 8; ++it) {
        int row = it * 16 + (tid >> 4);
        int k   = tid & 15;
        half8 vr = *(const half8*)(Es + row * 160 + k * 8);
        *(half8*)(ovt + ((size_t)(b * 768 + n0 + row)) * 2048 + s0 + k * 8) = vr;
      }
    } else {
      _Float16* O = (z == 0) ? oq : ok;
      const float scale = (z == 0) ? LOG2E : 1.0f;
      #pragma unroll
      for (int j = 0; j < 4; ++j) {
        int n_loc = wc * 64 + j * 16 + qd * 4;
        float4 bb = *(const float4*)(bias + n0 + n_loc);
        #pragma unroll
        for (int i = 0; i < 4; ++i) {
          int s_loc = wr * 64 + i * 16 + col;
          half4v h = pack4((acc[i][j][0] + bb.x) * scale, (acc[i][j][1] + bb.y) * scale,
                           (acc[i][j][2] + bb.z) * scale, (acc[i][j][3] + bb.w) * scale);
          *(half4v*)(Es + s_loc * 160 + n_loc) = h;
        }
      }
      __syncthreads();
      const int hh0 = n0 >> 6;
      #pragma unroll
      for (int it = 0; it < 8; ++it) {
        int seg = it * 32 + (tid >> 3);
        int s = seg >> 1, hseg = seg & 1;
        int k = tid & 7;
        half8 vr = *(const half8*)(Es + s * 160 + hseg * 64 + k * 8);
        int mb = (m0 + s) >> 11, sg = (m0 + s) & 2047;
        *(half8*)(O + (size_t)(mb * 12 + hh0 + hseg) * 131072
                    + (size_t)sg * 64 + k * 8) = vr;
      }
    }
  }
}

// ---------------- kernel 3: flash attention, 32x32 permuted-PV (r12 base) ----
// r13 lesson: fusing both subtiles' softmax doubled live regs (VGPR 72->112),
// occupancy 25->17%, dur +7us. At this occupancy the live-register footprint
// outweighs instruction count. r14 = r12's per-subtile structure (94.6us,
// VGPR 72) + two register-neutral VALU cuts:
//  1. persistent nmv (splatted running max) fed as the C operand of each
//     subtile's first QK MFMA (C!=D legal; nmv stays live so D is allocated
//     separately -> the 16 seed v_movs per subtile vanish). +16 VGPR only.
//  2. per-subtile exp2 fast path: common case e=exp2(st), no "-mr" subtract
//     (st0/e0 dead before st1 exists -> no footprint growth, unlike r13).
// Data paths, PV permutation, epilogue: byte-identical to r12 (HW-proven).

__device__ __forceinline__ void stage_kv(const _Float16* __restrict__ Kg,
                                         const _Float16* __restrict__ Vg,
                                         _Float16* ksd, _Float16* vsd, int j0, int tid) {
  #pragma unroll
  for (int i = 0; i < 2; ++i) {
    int c = i * 256 + tid;
    int row = c >> 3, sc = c & 7;
    gl_lds16(Kg + (size_t)(j0 + row) * 64 + ((sc ^ (row & 7)) * 8), ksd + c * 8);
    gl_lds16(Vg + (size_t)row * 2048 + j0 + ((sc ^ (row & 7)) * 8), vsd + c * 8);
  }
}

// natural-order pack: words = (e0e1, e2e3, e4e5, e6e7); no cross-lane ops
__device__ __forceinline__ half8 pknat(const float* e) {
  union W { fp16x2 h; unsigned int u; };
  W w0, w1, w2, w3;
  w0.h = __builtin_amdgcn_cvt_pkrtz(e[0], e[1]);
  w1.h = __builtin_amdgcn_cvt_pkrtz(e[2], e[3]);
  w2.h = __builtin_amdgcn_cvt_pkrtz(e[4], e[5]);
  w3.h = __builtin_amdgcn_cvt_pkrtz(e[6], e[7]);
  union R { unsigned int w[4]; half8 v; } r;
  r.w[0] = w0.u; r.w[1] = w1.u; r.w[2] = w2.u; r.w[3] = w3.u;
  return r.v;
}

__device__ __forceinline__ float max16(const floatx16& s) {
  float m0 = fmaxf(fmaxf(s[0], s[1]),  fmaxf(s[2], s[3]));
  float m1 = fmaxf(fmaxf(s[4], s[5]),  fmaxf(s[6], s[7]));
  float m2 = fmaxf(fmaxf(s[8], s[9]),  fmaxf(s[10], s[11]));
  float m3 = fmaxf(fmaxf(s[12], s[13]), fmaxf(s[14], s[15]));
  return fmaxf(fmaxf(m0, m1), fmaxf(m2, m3));
}

// one 32-k subtile: QK (4 MFMA, C seeded from persistent nmv) -> online
// softmax (exp2 fast path) -> permuted PV (4 MFMA + 1 ones)
template <int SUB>
__device__ __forceinline__ void attn_sub32(
    const char* ksb, const char* vsb,
    const half8 (&qf)[4], const int (&kvb)[4], const int (&vgo)[8],
    const half8& vone, float& nm, floatx16& nmv, floatx16& lac, floatx16 (&o)[2])
{
  half8 kf0 = *(const half8*)(ksb + kvb[0]);
  floatx16 st = __builtin_amdgcn_mfma_f32_32x32x16_f16(kf0, qf[0], nmv, 0, 0, 0);
  #pragma unroll
  for (int ds = 1; ds < 4; ++ds) {
    half8 kf = *(const half8*)(ksb + kvb[ds]);
    st = __builtin_amdgcn_mfma_f32_32x32x16_f16(kf, qf[ds], st, 0, 0, 0);
  }

  // per-q tile max: per-lane tree + partner half (lanes lq,0 / lq,1)
  float v = max16(st);
  v = fmaxf(v, __shfl_xor(v, 32, 64));

  float e[16];
  if (__any(v > 0.f)) {            // rare: running max must move
    float mr = fmaxf(v, 0.f);
    float al = __builtin_amdgcn_exp2f(-mr);
    nm -= mr;
    #pragma unroll
    for (int i = 0; i < 16; ++i) nmv[i] = nm;
    lac *= al;
    o[0] *= al;
    o[1] *= al;
    #pragma unroll
    for (int i = 0; i < 16; ++i) e[i] = __builtin_amdgcn_exp2f(st[i] - mr);
  } else {                         // common: st already <= 0 (seeded with nm)
    #pragma unroll
    for (int i = 0; i < 16; ++i) e[i] = __builtin_amdgcn_exp2f(st[i]);
  }

  #pragma unroll
  for (int f = 0; f < 2; ++f) {
    half8 pf = pknat(e + 8 * f);
    #pragma unroll
    for (int dt = 0; dt < 2; ++dt) {
      half4v lo = *(const half4v*)(vsb + dt * 4096 + vgo[4 * SUB + 2 * f]);
      half4v hh = *(const half4v*)(vsb + dt * 4096 + vgo[4 * SUB + 2 * f + 1]);
      half8 vf = __builtin_shufflevector(lo, hh, 0, 1, 2, 3, 4, 5, 6, 7);
      o[dt] = __builtin_amdgcn_mfma_f32_32x32x16_f16(vf, pf, o[dt], 0, 0, 0);
    }
    lac = __builtin_amdgcn_mfma_f32_32x32x16_f16(vone, pf, lac, 0, 0, 0);
  }
}

template <int BUF>
__device__ __forceinline__ void attn_body(
    int jnext, const _Float16* __restrict__ Kg, const _Float16* __restrict__ Vg,
    _Float16* Ks, _Float16* Vs, int tid,
    const half8 (&qf)[4], const int (&kvb)[4], const int (&vgo)[8],
    const half8& vone, float& nm, floatx16& nmv, floatx16& lac, floatx16 (&o)[2])
{
  if (jnext < 2048)
    stage_kv(Kg, Vg, Ks + (1 - BUF) * 4096, Vs + (1 - BUF) * 4096, jnext, tid);

  const char* ksb = (const char*)Ks + BUF * 8192;
  const char* vsb = (const char*)Vs + BUF * 8192;
  attn_sub32<0>(ksb,        vsb, qf, kvb, vgo, vone, nm, nmv, lac, o);
  attn_sub32<1>(ksb + 4096, vsb, qf, kvb, vgo, vone, nm, nmv, lac, o);
  __syncthreads();
}

__global__ __launch_bounds__(256, 2) void attn_kernel(
    const _Float16* __restrict__ Qm,   // [48][2048][64] (log2e-scaled)
    const _Float16* __restrict__ Km,   // [48][2048][64]
    const _Float16* __restrict__ Vt,   // [48][64][2048]
    float* __restrict__ out)           // [4][2048][768]
{
  __shared__ __attribute__((aligned(16))) _Float16 Ks[2 * 4096];
  __shared__ __attribute__((aligned(16))) _Float16 Vs[2 * 4096];
  const int bh = blockIdx.x;                 // XCD = bh % 8 (48 % 8 == 0)
  const int q0 = blockIdx.y * 128;
  const int tid = threadIdx.x, lane = tid & 63, w = tid >> 6;
  const int lq = lane & 31, hi = lane >> 5, c7 = lq & 7;
  const int qrow = q0 + w * 32 + lq;
  const _Float16* Qg = Qm + (size_t)bh * 131072;
  const _Float16* Kg = Km + (size_t)bh * 131072;
  const _Float16* Vg = Vt + (size_t)bh * 131072;

  // Q fragments: B-operand Q^T[d][q=lq], d = ds*16 + hi*8 + [0..7]
  half8 qf[4];
  #pragma unroll
  for (int ds = 0; ds < 4; ++ds)
    qf[ds] = *(const half8*)(Qg + (size_t)qrow * 64 + ds * 16 + hi * 8);

  // K granule-offset table (granule 2ds+hi, XOR row&7)
  int kvb[4];
  #pragma unroll
  for (int j = 0; j < 4; ++j)
    kvb[j] = lq * 128 + (((j * 2 + hi) ^ c7) * 16);

  // V half-granule table: vgo[g] = b64 read of granule g, half hi
  int vgo[8];
  #pragma unroll
  for (int g = 0; g < 8; ++g)
    vgo[g] = lq * 128 + ((g ^ c7) * 16) + hi * 8;

  const half8 vone = {(_Float16)1.0f, (_Float16)1.0f, (_Float16)1.0f, (_Float16)1.0f,
                      (_Float16)1.0f, (_Float16)1.0f, (_Float16)1.0f, (_Float16)1.0f};

  float nm = 100.f;                // forces first-subtile rescale; flushes o,lac
  floatx16 nmv;
  floatx16 lac;
  floatx16 o[2];
  #pragma unroll
  for (int i = 0; i < 16; ++i) { nmv[i] = 100.f; lac[i] = 0.f; o[0][i] = 0.f; o[1][i] = 0.f; }

  stage_kv(Kg, Vg, Ks, Vs, 0, tid);
  __syncthreads();

  for (int jj = 0; jj < 2048; jj += 128) {
    attn_body<0>(jj + 64,  Kg, Vg, Ks, Vs, tid, qf, kvb, vgo, vone, nm, nmv, lac, o);
    attn_body<1>(jj + 128, Kg, Vg, Ks, Vs, tid, qf, kvb, vgo, vone, nm, nmv, lac, o);
  }

  // epilogue: l = lac[0] (all 16 regs equal: ones-row sums over j);
  // o[dt][reg] = O^T[d = (reg&3)+8*(reg>>2)+4*hi][q=lq]
  const int b = bh / 12, h = bh % 12;
  const float inv = 1.0f / lac[0];
  float* obase = out + ((size_t)b * 2048 + qrow) * 768 + h * 64;
  #pragma unroll
  for (int dt = 0; dt < 2; ++dt)
    #pragma unroll
    for (int rq = 0; rq < 4; ++rq) {
      floatx4 vv = { o[dt][4 * rq + 0] * inv, o[dt][4 * rq + 1] * inv,
                     o[dt][4 * rq + 2] * inv, o[dt][4 * rq + 3] * inv };
      *(floatx4*)(obase + dt * 32 + rq * 8 + hi * 4) = vv;
    }
}

// ---------------- launcher ----------------
extern "C" void kernel_launch(void* const* d_in, const int* in_sizes, int n_in,
                              void* d_out, int out_size, void* d_ws, size_t ws_size,
                              hipStream_t stream) {
  const float* q  = (const float*)d_in[0];
  const float* k  = (const float*)d_in[1];
  const float* v  = (const float*)d_in[2];
  const float* Wq = (const float*)d_in[3];
  const float* bq = (const float*)d_in[4];
  const float* Wk = (const float*)d_in[5];
  const float* bk = (const float*)d_in[6];
  const float* Wv = (const float*)d_in[7];
  const float* bv = (const float*)d_in[8];

  const size_t NX = 6291456;   // 4*2048*768
  const size_t NW = 589824;    // 768*768
  const size_t need_full = (6 * NX + 3 * NW) * sizeof(_Float16);   // ~79 MB
  const size_t need_min  = (3 * NX) * sizeof(_Float16);            // ~37.7 MB

  if (ws_size >= need_full) {
    _Float16* xh = (_Float16*)d_ws;            // X'  [3][8192][768] f16
    _Float16* wh = xh + 3 * NX;                // W'  [3][768][768]  f16
    _Float16* qh = wh + 3 * NW;                // Q'  [48][2048][64] (log2e-scaled)
    _Float16* kh = qh + NX;                    // K'  [48][2048][64]
    _Float16* vt = kh + NX;                    // V'^T [48][64][2048]

    CvtArgs ca;
    ca.sx[0] = q;  ca.sx[1] = k;  ca.sx[2] = v;
    ca.sw[0] = Wq; ca.sw[1] = Wk; ca.sw[2] = Wv;
    ca.dx = xh; ca.dw = wh;

    cvt_kernel<<<dim3(3360, 3), 256, 0, stream>>>(ca);
    qkv_gemm<<<dim3(1152), 256, 0, stream>>>(xh, wh, bq, bk, bv, qh, kh, vt);
    attn_kernel<<<dim3(48, 16), 256, 0, stream>>>(qh, kh, vt, (float*)d_out);
  } else if (ws_size >= need_min) {
    _Float16* qh = (_Float16*)d_ws;
    _Float16* kh = qh + NX;
    _Float16* vt = kh + NX;
    qkv_gemm_f32<<<dim3(512), 256, 0, stream>>>(q, k, v, Wq, Wk, Wv, bq, bk, bv, qh, kh, vt);
    attn_kernel<<<dim3(48, 16), 256, 0, stream>>>(qh, kh, vt, (float*)d_out);
  }
}

// Round 15
// 246.813 us; speedup vs baseline: 1.0706x; 1.0706x over previous
//
#include <hip/hip_runtime.h>
#include <stdint.h>

typedef _Float16 half8  __attribute__((ext_vector_type(8)));
typedef _Float16 half4v __attribute__((ext_vector_type(4)));
typedef float    floatx4 __attribute__((ext_vector_type(4)));

#define LOG2E 1.44269504088896340736f

// async global->LDS 16B copy (LDS dest must be wave-uniform base + lane*16)
__device__ __forceinline__ void gl_lds16(const _Float16* g, _Float16* l) {
  __builtin_amdgcn_global_load_lds(
      (__attribute__((address_space(1))) void*)g,
      (__attribute__((address_space(3))) void*)l, 16, 0, 0);
}

__device__ __forceinline__ half4v pack4(float a, float b, float c, float d) {
  auto lo = __builtin_amdgcn_cvt_pkrtz(a, b);
  auto hi = __builtin_amdgcn_cvt_pkrtz(c, d);
  return half4v{static_cast<_Float16>(lo[0]), static_cast<_Float16>(lo[1]),
                static_cast<_Float16>(hi[0]), static_cast<_Float16>(hi[1])};
}

// ---------------- kernel 1: fp32 -> f16 convert (X streams + weights) --------
// One pass: 3x X [8192x768] (3072 chunks each) + 3x W [768x768] (288 each).
struct CvtArgs {
  const float* sx[3];
  const float* sw[3];
  _Float16*    dx;     // [3][6291456]
  _Float16*    dw;     // [3][589824]
};

__global__ void cvt_kernel(CvtArgs a) {
  const int z  = blockIdx.y;
  const int bx = blockIdx.x;
  const float* src;
  _Float16*    dst;
  int base;
  if (bx < 3072) { src = a.sx[z]; dst = a.dx + (size_t)z * 6291456; base = bx * 2048; }
  else           { src = a.sw[z]; dst = a.dw + (size_t)z * 589824;  base = (bx - 3072) * 2048; }
  const int i = base + threadIdx.x * 8;
  const float4* s = (const float4*)(src + i);
  float4 v0 = s[0], v1 = s[1];
  half8 h = { (_Float16)v0.x, (_Float16)v0.y, (_Float16)v0.z, (_Float16)v0.w,
              (_Float16)v1.x, (_Float16)v1.y, (_Float16)v1.z, (_Float16)v1.w };
  *(half8*)(dst + i) = h;
}

// ---------------- kernel 2: QKV projection GEMM (f16 in, deep prefetch) ------
// Best-measured config (r7 = 247.7 us total): f16 inputs, global_load_lds
// staging of both panels, 3 LDS buffers, 2-body-deep prefetch, counted
// s_waitcnt vmcnt(4), raw s_barrier, grid (64,6,3). ~50 us (from 98).
// Granule map: slot G -> row r=G>>2, slot gl=G&3 holds source granule
// g = gl ^ ((r>>1)&3); fragment read slot = qd ^ ((row>>1)&3).

__device__ __forceinline__ void gemm_stage16(const _Float16* __restrict__ P,
                                             _Float16* sb, int r0, int k0, int tid) {
  #pragma unroll
  for (int i = 0; i < 2; ++i) {          // 128 rows x 32 halfs = 8KB
    int G = i * 256 + tid;
    int r = G >> 2, gl = G & 3;
    int g = gl ^ ((r >> 1) & 3);
    gl_lds16(P + (size_t)(r0 + r) * 768 + k0 + g * 8, sb + G * 8);
  }
}

template <int RB, int WB, int VM, bool PREF>
__device__ __forceinline__ void gemm_body(
    int kpre, const _Float16* __restrict__ X, const _Float16* __restrict__ W,
    _Float16* As, _Float16* Bs, int m0, int n0, int tid, int z,
    int wr, int wc, int qd, int col, floatx4 (&acc)[4][4])
{
  asm volatile("s_waitcnt vmcnt(%0)" :: "i"(VM) : "memory");
  __builtin_amdgcn_s_barrier();
  __builtin_amdgcn_sched_barrier(0);
  if (PREF) {
    gemm_stage16(X, As + WB * 4096, m0, kpre, tid);
    gemm_stage16(W, Bs + WB * 4096, n0, kpre, tid);
  }
  __builtin_amdgcn_sched_barrier(0);

  half8 af[4], bf[4];
  #pragma unroll
  for (int t = 0; t < 4; ++t) {
    int ra = wr * 64 + t * 16 + col;
    af[t] = *(const half8*)(As + RB * 4096 + ra * 32 + ((qd ^ ((ra >> 1) & 3)) * 8));
  }
  #pragma unroll
  for (int t = 0; t < 4; ++t) {
    int rb = wc * 64 + t * 16 + col;
    bf[t] = *(const half8*)(Bs + RB * 4096 + rb * 32 + ((qd ^ ((rb >> 1) & 3)) * 8));
  }
  if (z == 2) {
    #pragma unroll
    for (int i = 0; i < 4; ++i)
      #pragma unroll
      for (int j = 0; j < 4; ++j)
        acc[i][j] = __builtin_amdgcn_mfma_f32_16x16x32_f16(af[i], bf[j], acc[i][j], 0, 0, 0);
  } else {
    #pragma unroll
    for (int i = 0; i < 4; ++i)
      #pragma unroll
      for (int j = 0; j < 4; ++j)
        acc[i][j] = __builtin_amdgcn_mfma_f32_16x16x32_f16(bf[j], af[i], acc[i][j], 0, 0, 0);
  }
}

__global__ __launch_bounds__(256, 2) void qkv_gemm(
    const _Float16* __restrict__ xh,   // [3][8192][768] f16
    const _Float16* __restrict__ wh,   // [3][768][768]  f16
    const float* __restrict__ bqp, const float* __restrict__ bkp, const float* __restrict__ bvp,
    _Float16* __restrict__ oq, _Float16* __restrict__ ok, _Float16* __restrict__ ovt)
{
  __shared__ __attribute__((aligned(16))) char smem[49152];
  _Float16* As = (_Float16*)smem;                 // 3 bufs x 4096 f16 = 24 KB
  _Float16* Bs = (_Float16*)(smem + 24576);       // 3 bufs x 4096 f16 = 24 KB
  _Float16* Es = (_Float16*)smem;                 // epilogue 128 x 160 halfs = 40 KB

  const int z  = blockIdx.z;
  const _Float16* X = xh + (size_t)z * 6291456;
  const _Float16* W = wh + (size_t)z * 589824;
  const int m0 = blockIdx.x * 128, n0 = blockIdx.y * 128;
  const int tid  = threadIdx.x;
  const int lane = tid & 63, wid = tid >> 6;
  const int wr = wid >> 1, wc = wid & 1;
  const int qd = lane >> 4, col = lane & 15;

  const floatx4 z4 = {0.f, 0.f, 0.f, 0.f};
  floatx4 acc[4][4];
  #pragma unroll
  for (int i = 0; i < 4; ++i)
    #pragma unroll
    for (int j = 0; j < 4; ++j) acc[i][j] = z4;

  // prologue: stage k-tiles 0 and 1 into bufs 0 and 1 (8 gl_lds/thread)
  gemm_stage16(X, As,        m0, 0,  tid);
  gemm_stage16(W, Bs,        n0, 0,  tid);
  gemm_stage16(X, As + 4096, m0, 32, tid);
  gemm_stage16(W, Bs + 4096, n0, 32, tid);

  // 24 bodies (BK=32): body t waits vmcnt(4) [stage t oldest, t+1 in flight],
  // stages k-tile t+2 into buf (t+2)%3, computes from buf t%3.
  int jn = 64;
  #pragma unroll 1
  for (int it = 0; it < 7; ++it) {   // bodies t = 3*it .. 3*it+2  (t = 0..20)
    gemm_body<0, 2, 4, true>(jn,      X, W, As, Bs, m0, n0, tid, z, wr, wc, qd, col, acc);
    gemm_body<1, 0, 4, true>(jn + 32, X, W, As, Bs, m0, n0, tid, z, wr, wc, qd, col, acc);
    gemm_body<2, 1, 4, true>(jn + 64, X, W, As, Bs, m0, n0, tid, z, wr, wc, qd, col, acc);
    jn += 96;
  }
  gemm_body<0, 2, 4, true >(736, X, W, As, Bs, m0, n0, tid, z, wr, wc, qd, col, acc); // t=21
  gemm_body<1, 0, 4, false>(0,   X, W, As, Bs, m0, n0, tid, z, wr, wc, qd, col, acc); // t=22
  gemm_body<2, 1, 0, false>(0,   X, W, As, Bs, m0, n0, tid, z, wr, wc, qd, col, acc); // t=23

  __syncthreads();   // all waves done with As/Bs; Es (aliased) reusable

  const float* bias = (z == 0) ? bqp : ((z == 1) ? bkp : bvp);
  const int b = m0 >> 11, s0 = m0 & 2047;   // 128-row tile never crosses a batch
  if (z == 2) {
    // acc D[m(s)][n]: reg=4 consecutive s, col=n. Stage Es[n][s], copy coalesced.
    #pragma unroll
    for (int j = 0; j < 4; ++j) {
      int n_loc = wc * 64 + j * 16 + col;
      float bb = bias[n0 + n_loc];
      #pragma unroll
      for (int i = 0; i < 4; ++i) {
        int s_loc = wr * 64 + i * 16 + qd * 4;
        half4v h = pack4(acc[i][j][0] + bb, acc[i][j][1] + bb,
                         acc[i][j][2] + bb, acc[i][j][3] + bb);
        *(half4v*)(Es + n_loc * 160 + s_loc) = h;
      }
    }
    __syncthreads();
    #pragma unroll
    for (int it = 0; it < 8; ++it) {
      int row = it * 16 + (tid >> 4);          // n index 0..127
      int k   = tid & 15;                      // 16B chunk within 128 s
      half8 vr = *(const half8*)(Es + row * 160 + k * 8);
      *(half8*)(ovt + ((size_t)(b * 768 + n0 + row)) * 2048 + s0 + k * 8) = vr;
    }
  } else {
    // swapped acc D[n][s]: reg=4 consecutive n(d), col=s. Stage Es[s][n], copy coalesced.
    _Float16* O = (z == 0) ? oq : ok;
    const float scale = (z == 0) ? LOG2E : 1.0f;  // fold log2e into Q
    #pragma unroll
    for (int j = 0; j < 4; ++j) {
      int n_loc = wc * 64 + j * 16 + qd * 4;
      float4 bb = *(const float4*)(bias + n0 + n_loc);
      #pragma unroll
      for (int i = 0; i < 4; ++i) {
        int s_loc = wr * 64 + i * 16 + col;
        half4v h = pack4((acc[i][j][0] + bb.x) * scale, (acc[i][j][1] + bb.y) * scale,
                         (acc[i][j][2] + bb.z) * scale, (acc[i][j][3] + bb.w) * scale);
        *(half4v*)(Es + s_loc * 160 + n_loc) = h;
      }
    }
    __syncthreads();
    const int hh0 = n0 >> 6;
    #pragma unroll
    for (int it = 0; it < 8; ++it) {
      int seg = it * 32 + (tid >> 3);          // 256 segments: (s, head-half)
      int s = seg >> 1, hseg = seg & 1;
      int k = tid & 7;
      half8 vr = *(const half8*)(Es + s * 160 + hseg * 64 + k * 8);
      int mb = (m0 + s) >> 11, sg = (m0 + s) & 2047;
      *(half8*)(O + (size_t)(mb * 12 + hh0 + hseg) * 131072
                  + (size_t)sg * 64 + k * 8) = vr;
    }
  }
}

// ---------------- fallback QKV (r6 persistent, fp32 inputs) ------------------
// Used only if ws_size can't hold the f16 input mirrors.

__device__ __forceinline__ void issue_panel(const float* __restrict__ P,
                                            int r0, int k0, int tid,
                                            float4& a0, float4& a1,
                                            float4& b0, float4& b1) {
  {
    int G = tid;
    int r = G >> 2, gl = G & 3;
    int g = gl ^ ((r >> 1) & 3);
    const float4* s = (const float4*)(P + (size_t)(r0 + r) * 768 + k0 + g * 8);
    a0 = s[0]; a1 = s[1];
  }
  {
    int G = 256 + tid;
    int r = G >> 2, gl = G & 3;
    int g = gl ^ ((r >> 1) & 3);
    const float4* s = (const float4*)(P + (size_t)(r0 + r) * 768 + k0 + g * 8);
    b0 = s[0]; b1 = s[1];
  }
}

__device__ __forceinline__ void write_panel(_Float16* sb, int tid,
                                            const float4& a0, const float4& a1,
                                            const float4& b0, const float4& b1) {
  half8 h0 = { (_Float16)a0.x, (_Float16)a0.y, (_Float16)a0.z, (_Float16)a0.w,
               (_Float16)a1.x, (_Float16)a1.y, (_Float16)a1.z, (_Float16)a1.w };
  *(half8*)(sb + tid * 8) = h0;
  half8 h1 = { (_Float16)b0.x, (_Float16)b0.y, (_Float16)b0.z, (_Float16)b0.w,
               (_Float16)b1.x, (_Float16)b1.y, (_Float16)b1.z, (_Float16)b1.w };
  *(half8*)(sb + (256 + tid) * 8) = h1;
}

template <int BUF>
__device__ __forceinline__ void gemm_body_f32(
    int knext, const float* __restrict__ X, const float* __restrict__ W,
    _Float16* As, _Float16* Bs, int m0, int n0, int tid, int z,
    int wr, int wc, int qd, int col, floatx4 (&acc)[4][4])
{
  const bool pref = (knext < 768);
  float4 xa0, xa1, xb0, xb1, wa0, wa1, wb0, wb1;
  if (pref) {
    issue_panel(X, m0, knext, tid, xa0, xa1, xb0, xb1);
    issue_panel(W, n0, knext, tid, wa0, wa1, wb0, wb1);
  }

  half8 af[4], bf[4];
  #pragma unroll
  for (int t = 0; t < 4; ++t) {
    int ra = wr * 64 + t * 16 + col;
    af[t] = *(const half8*)(As + BUF * 4096 + ra * 32 + ((qd ^ ((ra >> 1) & 3)) * 8));
  }
  #pragma unroll
  for (int t = 0; t < 4; ++t) {
    int rb = wc * 64 + t * 16 + col;
    bf[t] = *(const half8*)(Bs + BUF * 4096 + rb * 32 + ((qd ^ ((rb >> 1) & 3)) * 8));
  }
  if (z == 2) {
    #pragma unroll
    for (int i = 0; i < 4; ++i)
      #pragma unroll
      for (int j = 0; j < 4; ++j)
        acc[i][j] = __builtin_amdgcn_mfma_f32_16x16x32_f16(af[i], bf[j], acc[i][j], 0, 0, 0);
  } else {
    #pragma unroll
    for (int i = 0; i < 4; ++i)
      #pragma unroll
      for (int j = 0; j < 4; ++j)
        acc[i][j] = __builtin_amdgcn_mfma_f32_16x16x32_f16(bf[j], af[i], acc[i][j], 0, 0, 0);
  }

  if (pref) {
    write_panel(As + (1 - BUF) * 4096, tid, xa0, xa1, xb0, xb1);
    write_panel(Bs + (1 - BUF) * 4096, tid, wa0, wa1, wb0, wb1);
  }
  __syncthreads();
}

__global__ __launch_bounds__(256, 2) void qkv_gemm_f32(
    const float* __restrict__ qx, const float* __restrict__ kx, const float* __restrict__ vx,
    const float* __restrict__ Wqp, const float* __restrict__ Wkp, const float* __restrict__ Wvp,
    const float* __restrict__ bqp, const float* __restrict__ bkp, const float* __restrict__ bvp,
    _Float16* __restrict__ oq, _Float16* __restrict__ ok, _Float16* __restrict__ ovt)
{
  __shared__ __attribute__((aligned(16))) char smem[40960];
  _Float16* As = (_Float16*)smem;
  _Float16* Bs = (_Float16*)(smem + 16384);
  _Float16* Es = (_Float16*)smem;

  const int tid  = threadIdx.x;
  const int lane = tid & 63, wid = tid >> 6;
  const int wr = wid >> 1, wc = wid & 1;
  const int qd = lane >> 4, col = lane & 15;

  #pragma unroll 1
  for (int t = blockIdx.x; t < 1152; t += 512) {
    const int m0 = (t & 63) * 128;
    const int n0 = ((t >> 6) % 6) * 128;
    const int z  = t / 384;
    const float* X = (z == 0) ? qx : ((z == 1) ? kx : vx);
    const float* W = (z == 0) ? Wqp : ((z == 1) ? Wkp : Wvp);

    const floatx4 z4 = {0.f, 0.f, 0.f, 0.f};
    floatx4 acc[4][4];
    #pragma unroll
    for (int i = 0; i < 4; ++i)
      #pragma unroll
      for (int j = 0; j < 4; ++j) acc[i][j] = z4;

    {
      float4 xa0, xa1, xb0, xb1, wa0, wa1, wb0, wb1;
      issue_panel(X, m0, 0, tid, xa0, xa1, xb0, xb1);
      issue_panel(W, n0, 0, tid, wa0, wa1, wb0, wb1);
      __syncthreads();
      write_panel(As, tid, xa0, xa1, xb0, xb1);
      write_panel(Bs, tid, wa0, wa1, wb0, wb1);
    }
    __syncthreads();
    for (int kk = 0; kk < 768; kk += 64) {
      gemm_body_f32<0>(kk + 32, X, W, As, Bs, m0, n0, tid, z, wr, wc, qd, col, acc);
      gemm_body_f32<1>(kk + 64, X, W, As, Bs, m0, n0, tid, z, wr, wc, qd, col, acc);
    }

    const float* bias = (z == 0) ? bqp : ((z == 1) ? bkp : bvp);
    const int b = m0 >> 11, s0 = m0 & 2047;
    if (z == 2) {
      #pragma unroll
      for (int j = 0; j < 4; ++j) {
        int n_loc = wc * 64 + j * 16 + col;
        float bb = bias[n0 + n_loc];
        #pragma unroll
        for (int i = 0; i < 4; ++i) {
          int s_loc = wr * 64 + i * 16 + qd * 4;
          half4v h = pack4(acc[i][j][0] + bb, acc[i][j][1] + bb,
                           acc[i][j][2] + bb, acc[i][j][3] + bb);
          *(half4v*)(Es + n_loc * 160 + s_loc) = h;
        }
      }
      __syncthreads();
      #pragma unroll
      for (int it = 0; it < 8; ++it) {
        int row = it * 16 + (tid >> 4);
        int k   = tid & 15;
        half8 vr = *(const half8*)(Es + row * 160 + k * 8);
        *(half8*)(ovt + ((size_t)(b * 768 + n0 + row)) * 2048 + s0 + k * 8) = vr;
      }
    } else {
      _Float16* O = (z == 0) ? oq : ok;
      const float scale = (z == 0) ? LOG2E : 1.0f;
      #pragma unroll
      for (int j = 0; j < 4; ++j) {
        int n_loc = wc * 64 + j * 16 + qd * 4;
        float4 bb = *(const float4*)(bias + n0 + n_loc);
        #pragma unroll
        for (int i = 0; i < 4; ++i) {
          int s_loc = wr * 64 + i * 16 + col;
          half4v h = pack4((acc[i][j][0] + bb.x) * scale, (acc[i][j][1] + bb.y) * scale,
                           (acc[i][j][2] + bb.z) * scale, (acc[i][j][3] + bb.w) * scale);
          *(half4v*)(Es + s_loc * 160 + n_loc) = h;
        }
      }
      __syncthreads();
      const int hh0 = n0 >> 6;
      #pragma unroll
      for (int it = 0; it < 8; ++it) {
        int seg = it * 32 + (tid >> 3);
        int s = seg >> 1, hseg = seg & 1;
        int k = tid & 7;
        half8 vr = *(const half8*)(Es + s * 160 + hseg * 64 + k * 8);
        int mb = (m0 + s) >> 11, sg = (m0 + s) & 2047;
        *(half8*)(O + (size_t)(mb * 12 + hh0 + hseg) * 131072
                    + (size_t)sg * 64 + k * 8) = vr;
      }
    }
  }
}

// ---------------- kernel 3: flash attention (r0 verbatim — measured best) ----
// Plateau evidence: r0 (16x16) = r12 (32x32 permuted-PV) = ~94.5us across
// structurally distinct designs; r11/r13/r14 regressed via DS-pipe or VGPR
// pressure; r2/r3 sync variants null. Issue-saturated: MFMA+VALU ~84%.
// VGPR sweet spot is <=80 — do not grow the register footprint.

__device__ __forceinline__ void stage_kv(const _Float16* __restrict__ Kg,
                                         const _Float16* __restrict__ Vg,
                                         _Float16* ksd, _Float16* vsd, int j0, int tid) {
  #pragma unroll
  for (int i = 0; i < 2; ++i) {
    int c = i * 256 + tid;
    int row = c >> 3, sc = c & 7;
    gl_lds16(Kg + (size_t)(j0 + row) * 64 + ((sc ^ (row & 7)) * 8), ksd + c * 8);
    gl_lds16(Vg + (size_t)row * 2048 + j0 + ((sc ^ (row & 7)) * 8), vsd + c * 8);
  }
}

template <int BUF>
__device__ __forceinline__ void attn_body(
    int jnext, const _Float16* __restrict__ Kg, const _Float16* __restrict__ Vg,
    _Float16* Ks, _Float16* Vs, int tid,
    const half8 (&qf)[2][2], int kb0, int kb1, const int (&vb)[4],
    floatx4 (&negm)[2], floatx4 (&ol)[2], floatx4 (&o)[4][2])
{
  if (jnext < 2048)
    stage_kv(Kg, Vg, Ks + (1 - BUF) * 4096, Vs + (1 - BUF) * 4096, jnext, tid);

  const char* ksb = (const char*)Ks;
  const char* vsb = (const char*)Vs;

  // S^T - m = K . Q^T + (-m) : C seeded with negm, contraction d=64 in 2 steps
  floatx4 st[4][2];
  #pragma unroll
  for (int t = 0; t < 4; ++t) {
    half8 kf0 = *(const half8*)(ksb + BUF * 8192 + t * 2048 + kb0);
    half8 kf1 = *(const half8*)(ksb + BUF * 8192 + t * 2048 + kb1);
    #pragma unroll
    for (int qt = 0; qt < 2; ++qt) {
      st[t][qt] = __builtin_amdgcn_mfma_f32_16x16x32_f16(kf0, qf[qt][0], negm[qt], 0, 0, 0);
      st[t][qt] = __builtin_amdgcn_mfma_f32_16x16x32_f16(kf1, qf[qt][1], st[t][qt], 0, 0, 0);
    }
  }

  // tile max of (s - m); mr>0 only when running max must update (rare after warm-up)
  float mr[2];
  #pragma unroll
  for (int qt = 0; qt < 2; ++qt) {
    float v = fmaxf(
        fmaxf(fmaxf(fmaxf(st[0][qt][0], st[0][qt][1]), fmaxf(st[0][qt][2], st[0][qt][3])),
              fmaxf(fmaxf(st[1][qt][0], st[1][qt][1]), fmaxf(st[1][qt][2], st[1][qt][3]))),
        fmaxf(fmaxf(fmaxf(st[2][qt][0], st[2][qt][1]), fmaxf(st[2][qt][2], st[2][qt][3])),
              fmaxf(fmaxf(st[3][qt][0], st[3][qt][1]), fmaxf(st[3][qt][2], st[3][qt][3]))));
    v = fmaxf(v, __shfl_xor(v, 16, 64));
    v = fmaxf(v, __shfl_xor(v, 32, 64));
    mr[qt] = fmaxf(v, 0.f);
  }

  // single pf path (consumes st immediately; mr is usually 0)
  half4v pf[4][2];
  #pragma unroll
  for (int qt = 0; qt < 2; ++qt)
    #pragma unroll
    for (int t = 0; t < 4; ++t)
      pf[t][qt] = pack4(__builtin_amdgcn_exp2f(st[t][qt][0] - mr[qt]),
                        __builtin_amdgcn_exp2f(st[t][qt][1] - mr[qt]),
                        __builtin_amdgcn_exp2f(st[t][qt][2] - mr[qt]),
                        __builtin_amdgcn_exp2f(st[t][qt][3] - mr[qt]));

  // rare rescale: touches only already-live registers
  if (__any(mr[0] > 0.f || mr[1] > 0.f)) {
    #pragma unroll
    for (int qt = 0; qt < 2; ++qt) {
      float al = __builtin_amdgcn_exp2f(-mr[qt]);
      negm[qt] -= mr[qt];
      ol[qt] *= al;
      #pragma unroll
      for (int dt = 0; dt < 4; ++dt) o[dt][qt] *= al;
    }
  }

  // PV: out^T = V^T . P (K=16, P straight from regs) + ones-row MFMA accumulates l
  const half4v vone = {(_Float16)1.0f, (_Float16)1.0f, (_Float16)1.0f, (_Float16)1.0f};
  #pragma unroll
  for (int dt = 0; dt < 4; ++dt) {
    #pragma unroll
    for (int t = 0; t < 4; ++t) {
      half4v vf = *(const half4v*)(vsb + BUF * 8192 + dt * 2048 + vb[t]);
      #pragma unroll
      for (int qt = 0; qt < 2; ++qt)
        o[dt][qt] = __builtin_amdgcn_mfma_f32_16x16x16f16(vf, pf[t][qt], o[dt][qt], 0, 0, 0);
    }
  }
  #pragma unroll
  for (int t = 0; t < 4; ++t)
    #pragma unroll
    for (int qt = 0; qt < 2; ++qt)
      ol[qt] = __builtin_amdgcn_mfma_f32_16x16x16f16(vone, pf[t][qt], ol[qt], 0, 0, 0);

  __syncthreads();
}

__global__ __launch_bounds__(256, 3) void attn_kernel(
    const _Float16* __restrict__ Qm,   // [48][2048][64] (log2e-scaled)
    const _Float16* __restrict__ Km,   // [48][2048][64]
    const _Float16* __restrict__ Vt,   // [48][64][2048]
    float* __restrict__ out)           // [4][2048][768]
{
  __shared__ __attribute__((aligned(16))) _Float16 Ks[2 * 4096];
  __shared__ __attribute__((aligned(16))) _Float16 Vs[2 * 4096];
  const int bh = blockIdx.x;                 // XCD = bh % 8 (48 % 8 == 0)
  const int q0 = blockIdx.y * 128;
  const int tid = threadIdx.x, lane = tid & 63, w = tid >> 6;
  const int qd = lane >> 4, col = lane & 15, c7 = col & 7;
  const _Float16* Qg = Qm + (size_t)bh * 131072;
  const _Float16* Kg = Km + (size_t)bh * 131072;
  const _Float16* Vg = Vt + (size_t)bh * 131072;

  // Q fragments direct from global (kept in regs for the whole kernel)
  half8 qf[2][2];
  #pragma unroll
  for (int qt = 0; qt < 2; ++qt)
    #pragma unroll
    for (int ks = 0; ks < 2; ++ks)
      qf[qt][ks] = *(const half8*)(Qg + (size_t)(q0 + w * 32 + qt * 16 + col) * 64
                                   + (ks * 4 + qd) * 8);

  // loop-invariant per-lane LDS byte offsets (tile offsets fold into ds_read immediates)
  const int kb0 = col * 128 + ((qd ^ c7) * 16);
  const int kb1 = col * 128 + (((4 + qd) ^ c7) * 16);
  const int vq = (qd >> 1) ^ c7;
  int vb[4];
  #pragma unroll
  for (int t = 0; t < 4; ++t)
    vb[t] = col * 128 + (qd & 1) * 8 + ((vq ^ (2 * t)) * 16);

  // negm init +100: first tile st = s+100 finite, mr>0 forced; alpha flushes to 0
  floatx4 negm[2] = {{100.f, 100.f, 100.f, 100.f}, {100.f, 100.f, 100.f, 100.f}};
  const floatx4 z4 = {0.f, 0.f, 0.f, 0.f};
  floatx4 ol[2] = {z4, z4};
  floatx4 o[4][2];
  #pragma unroll
  for (int dt = 0; dt < 4; ++dt)
    #pragma unroll
    for (int qt = 0; qt < 2; ++qt) o[dt][qt] = z4;

  stage_kv(Kg, Vg, Ks, Vs, 0, tid);
  __syncthreads();

  for (int jj = 0; jj < 2048; jj += 128) {
    attn_body<0>(jj + 64,  Kg, Vg, Ks, Vs, tid, qf, kb0, kb1, vb, negm, ol, o);
    attn_body<1>(jj + 128, Kg, Vg, Ks, Vs, tid, qf, kb0, kb1, vb, negm, ol, o);
  }

  // epilogue: l comes out of the ones-MFMA accumulator (all 4 regs equal, col=q)
  const int b = bh / 12, h = bh % 12;
  #pragma unroll
  for (int qt = 0; qt < 2; ++qt) {
    float inv = 1.0f / ol[qt][0];
    int qg = q0 + w * 32 + qt * 16 + col;
    float* obase = out + ((size_t)b * 2048 + qg) * 768 + h * 64;
    #pragma unroll
    for (int dt = 0; dt < 4; ++dt) {
      floatx4 v = o[dt][qt];
      v *= inv;
      *(floatx4*)(obase + dt * 16 + qd * 4) = v;
    }
  }
}

// ---------------- launcher ----------------
extern "C" void kernel_launch(void* const* d_in, const int* in_sizes, int n_in,
                              void* d_out, int out_size, void* d_ws, size_t ws_size,
                              hipStream_t stream) {
  const float* q  = (const float*)d_in[0];
  const float* k  = (const float*)d_in[1];
  const float* v  = (const float*)d_in[2];
  const float* Wq = (const float*)d_in[3];
  const float* bq = (const float*)d_in[4];
  const float* Wk = (const float*)d_in[5];
  const float* bk = (const float*)d_in[6];
  const float* Wv = (const float*)d_in[7];
  const float* bv = (const float*)d_in[8];

  const size_t NX = 6291456;   // 4*2048*768
  const size_t NW = 589824;    // 768*768
  const size_t need_full = (6 * NX + 3 * NW) * sizeof(_Float16);   // ~79 MB
  const size_t need_min  = (3 * NX) * sizeof(_Float16);            // ~37.7 MB

  if (ws_size >= need_full) {
    _Float16* xh = (_Float16*)d_ws;            // X'  [3][8192][768] f16
    _Float16* wh = xh + 3 * NX;                // W'  [3][768][768]  f16
    _Float16* qh = wh + 3 * NW;                // Q'  [48][2048][64] (log2e-scaled)
    _Float16* kh = qh + NX;                    // K'  [48][2048][64]
    _Float16* vt = kh + NX;                    // V'^T [48][64][2048]

    CvtArgs ca;
    ca.sx[0] = q;  ca.sx[1] = k;  ca.sx[2] = v;
    ca.sw[0] = Wq; ca.sw[1] = Wk; ca.sw[2] = Wv;
    ca.dx = xh; ca.dw = wh;

    cvt_kernel<<<dim3(3360, 3), 256, 0, stream>>>(ca);
    qkv_gemm<<<dim3(64, 6, 3), 256, 0, stream>>>(xh, wh, bq, bk, bv, qh, kh, vt);
    attn_kernel<<<dim3(48, 16), 256, 0, stream>>>(qh, kh, vt, (float*)d_out);
  } else if (ws_size >= need_min) {
    _Float16* qh = (_Float16*)d_ws;
    _Float16* kh = qh + NX;
    _Float16* vt = kh + NX;
    qkv_gemm_f32<<<dim3(512), 256, 0, stream>>>(q, k, v, Wq, Wk, Wv, bq, bk, bv, qh, kh, vt);
    attn_kernel<<<dim3(48, 16), 256, 0, stream>>>(qh, kh, vt, (float*)d_out);
  }
}